// Round 4
// baseline (449.290 us; speedup 1.0000x reference)
//
#include <hip/hip_runtime.h>

typedef _Float16 hv8 __attribute__((ext_vector_type(8)));  // 8 fp16 = 4 VGPRs MFMA A/B frag
typedef float    fv4 __attribute__((ext_vector_type(4)));  // 4 fp32 MFMA C/D frag
typedef unsigned int u32;

#define DEVI __device__ __forceinline__

static constexpr int T_   = 200;
static constexpr int ROWS = 8;      // batch rows per block (512 blocks, 2 blocks/CU)
static constexpr int WS   = 104;    // weight row stride in halfs (208 B, 16B-aligned)
static constexpr int BTOT = 4096;

// Feed slabs carved into poolH after weight frags move to registers (offsets in halfs).
static constexpr int F1o = 0;      // [2 par][2 g][16 b][16 u]  h1 feed  w0 -> w1,w2
static constexpr int F2o = 1024;   // [2 par][2 g][16 b][32 u]  h2 feed  w1,w2 -> w3
static constexpr int XAo = 3072;   // [2 slot][16 b][16 u]      w1 own h2 (units 0:16)  read by w2
static constexpr int XBo = 3584;   // [2 slot][16 b][16 u]      w2 own h2 (units 16:32) read by w1
static constexpr int F3o = 4096;   // [2 slot][16 b][16 u]      h3 (epilogue reads slot 1)
static constexpr int F_TOTAL = 4608;

#if __has_builtin(__builtin_amdgcn_rcpf)
DEVI float frcp(float x) { return __builtin_amdgcn_rcpf(x); }
#else
DEVI float frcp(float x) { return 1.0f / x; }
#endif
DEVI float fsig(float x)  { return frcp(1.0f + __expf(-x)); }                          // inf-safe -> 0/1
DEVI float ftanh(float x) { float e = __expf(2.0f * x); return 1.0f - 2.0f * frcp(e + 1.0f); } // -> -1/1

DEVI u32 pk2h(float a, float b) {     // pack two fp32 -> fp16x2 (RNE via v_cvt_f16_f32)
    union { _Float16 h[2]; u32 u; } cv;
    cv.h[0] = (_Float16)a; cv.h[1] = (_Float16)b;
    return cv.u;
}

union HU { hv8 h; u32 u[4]; };

// ---------------- fused 3-layer LSTM + collapsed linear head ----------------
// Swapped-operand MFMA: A = weights (m=gate-row), B = activations (k=feature, n=batch).
// Per interval (2 timesteps), each wave FIRST computes the input projection
// Gx = Wih·(x|h_prev_layer) + bias with OFF-CHAIN MFMAs straight into the
// accumulator (inputs available post-barrier), then runs the serial chain as
// exactly: 4 ds_bpermute -> one k=32 MFMA per gate-tile (C-in = Gx) ->
// activations -> pack. Barriers drain lgkmcnt only (LDS visibility); vmcnt
// drains at the per-wave x-prefetch use point (1 interval of slack).
__global__ __launch_bounds__(256, 2) void lstm_fused(
    const float* __restrict__ xg,
    const float* __restrict__ Wih1, const float* __restrict__ Whh1,
    const float* __restrict__ bih1, const float* __restrict__ bhh1,
    const float* __restrict__ Wih2, const float* __restrict__ Whh2,
    const float* __restrict__ bih2, const float* __restrict__ bhh2,
    const float* __restrict__ Wih3, const float* __restrict__ Whh3,
    const float* __restrict__ bih3, const float* __restrict__ bhh3,
    const float* __restrict__ W_fc1, const float* __restrict__ b_fc1,
    const float* __restrict__ W_fc2, const float* __restrict__ b_fc2,
    const float* __restrict__ W_cls, const float* __restrict__ b_cls,
    float* __restrict__ outp)
{
    // poolH: weights [256 rows][WS] fp16 during prologue; feed slabs carved in afterwards
    __shared__ __align__(16) _Float16 poolH[256 * WS];       // 53248 B
    __shared__ float T2s[512];   // [32][16] = W_fc2 @ W_fc1
    __shared__ float t2vs[32];   // b_fc2 + W_fc2 @ b_fc1
    __shared__ float Msh[96];    // [16][6] collapsed head matrix
    __shared__ float vsh[6];     // collapsed head bias

    const int tid  = threadIdx.x;
    const int wid  = tid >> 6;       // 0=L1, 1/2=L2 halves, 3=L3
    const int lane = tid & 63;
    const int nl   = lane & 15;
    const int quad = lane >> 4;
    const int b0   = blockIdx.x * ROWS;

    // ---- stage weights (fp32 -> fp16) as rows [gate-row][k] ----
    // Column map per wave row (k):
    //  w0: [0:36) Wih1 | 36 bias1 | [64:80) Whh1 | else 0
    //  w1: [0:16) Wih2 | 16 bias2 | [64:80) Whh2 own u0:16 | [80:96) other u16:32 | else 0
    //  w2: [0:16) Wih2 | 16 bias2 | [64:80) Whh2 own u16:32 | [80:96) other u0:16 | else 0
    //  w3: [0:32) Wih3 | [64:80) Whh3 | 80 bias3 | else 0
    for (int idx = tid; idx < 256 * WS; idx += 256) {
        int n = idx / WS, k = idx - n * WS;
        int w = n >> 6, r = n & 63;
        int g = r >> 4, u = r & 15;
        float v = 0.f;
        if (w == 0) {
            int row = g * 16 + u;
            if (k < 36)       v = Wih1[row * 36 + k];
            else if (k == 36) v = bih1[row] + bhh1[row];
            else if (k >= 64 && k < 80) v = Whh1[row * 16 + (k - 64)];
        } else if (w <= 2) {
            int row = g * 32 + (w - 1) * 16 + u;
            if (k < 16)       v = Wih2[row * 16 + k];
            else if (k == 16) v = bih2[row] + bhh2[row];
            else if (k >= 64 && k < 96) {
                int kk = k - 64;   // 0..31 = [own 0..15 | other 16..31]
                int uu = (w == 1) ? kk : ((kk < 16) ? kk + 16 : kk - 16);
                v = Whh2[row * 32 + uu];
            }
        } else {
            int row = g * 16 + u;
            if (k < 32)       v = Wih3[row * 32 + k];
            else if (k >= 64 && k < 80) v = Whh3[row * 16 + (k - 64)];
            else if (k == 80) v = bih3[row] + bhh3[row];
        }
        poolH[idx] = (_Float16)v;
    }
    // head: T2 = W_fc2 @ W_fc1 (fp32; 24KB weights, L2-resident)
    for (int idx = tid; idx < 512; idx += 256) {
        int b = idx >> 4, u = idx & 15;
        float acc = 0.f;
        for (int a = 0; a < 128; ++a) acc += W_fc2[b * 128 + a] * W_fc1[a * 16 + u];
        T2s[idx] = acc;
    }
    if (tid < 32) {
        float acc = b_fc2[tid];
        for (int a = 0; a < 128; ++a) acc += W_fc2[tid * 128 + a] * b_fc1[a];
        t2vs[tid] = acc;
    }
    __syncthreads();

    // ---- per-wave register-resident weight A-frags ----
    // WI0: Gx kt0 (cols 0..31); WI1 (w0 only): Gx kt1 (cols 32..63); WH: chain (cols 64..95)
    hv8 WI0[4], WI1[4], WH[4];
    #pragma unroll
    for (int mt = 0; mt < 4; ++mt) {
        const int base = (wid * 64 + mt * 16 + nl) * WS;
        WI0[mt] = *(const hv8*)&poolH[base + quad * 8];
        WH[mt]  = *(const hv8*)&poolH[base + 64 + quad * 8];
    }
    if (wid == 0) {
        #pragma unroll
        for (int mt = 0; mt < 4; ++mt)
            WI1[mt] = *(const hv8*)&poolH[(mt * 16 + nl) * WS + 32 + quad * 8];
    }
    // collapsed head: M[u][j] = sum_b Wc[j][b]*T2[b][u];  v[j] = bc[j] + sum_b Wc[j][b]*t2v[b]
    if (tid < 96) {
        int u = tid / 6, j = tid - (tid / 6) * 6;
        float acc = 0.f;
        for (int b = 0; b < 32; ++b) acc += W_cls[j * 32 + b] * T2s[b * 16 + u];
        Msh[u * 6 + j] = acc;
    }
    if (tid < 6) {
        float acc = b_cls[tid];
        for (int b = 0; b < 32; ++b) acc += W_cls[tid * 32 + b] * t2vs[b];
        vsh[tid] = acc;
    }
    __syncthreads();   // weights now in registers; pool reusable

    // ---- zero feed slabs + prologue x loads (t=0..3) ----
    for (int idx = tid; idx < F_TOTAL; idx += 256) poolH[idx] = (_Float16)0.f;

    fv4 xc[2][3], xn[2][3];            // w0 only: [g][chunk] feats q*8..+3, +4..+7, 32..35
    const float* xb = xg;
    if (wid == 0) {
        int xr = b0 + nl; if (xr > BTOT - 1) xr = BTOT - 1;   // nl 8..15: duplicate cols, clamped
        xb = xg + (size_t)xr * T_ * 36;
        #pragma unroll
        for (int g = 0; g < 2; ++g) {
            xc[g][0] = *(const fv4*)(xb + g * 36 + quad * 8);
            xc[g][1] = *(const fv4*)(xb + g * 36 + quad * 8 + 4);
            xc[g][2] = *(const fv4*)(xb + g * 36 + 32);
            xn[g][0] = *(const fv4*)(xb + (2 + g) * 36 + quad * 8);
            xn[g][1] = *(const fv4*)(xb + (2 + g) * 36 + quad * 8 + 4);
            xn[g][2] = *(const fv4*)(xb + (2 + g) * 36 + 32);
        }
    }
    __syncthreads();

    u32 pk01 = 0, pk23 = 0;                 // own h(t-1), packed fp16 pairs (units q*4+0,1 | +2,3)
    float c_st[4] = {0.f, 0.f, 0.f, 0.f};   // cell state: unit quad*4+r, batch nl
    const int s1x4 = ((quad & 1) * 32 + nl) * 4;   // bpermute byte indices
    const int s2x4 = s1x4 + 64;
    const u32 BIAS1 = 0x00003C00u;          // fp16 1.0 in low half
    const fv4 Z4 = (fv4){0.f, 0.f, 0.f, 0.f};

// One serial timestep: shuffles -> chain MFMA (C-in = Gx) -> act -> pack -> feeds.
// CARR: this step's accumulator (holds Gx); G: 0/1 literal within interval.
#define DO_STEP(CARR, G)                                                              \
    {                                                                                 \
        u32 sA = (u32)__builtin_amdgcn_ds_bpermute(s1x4, (int)pk01);                  \
        u32 sB = (u32)__builtin_amdgcn_ds_bpermute(s1x4, (int)pk23);                  \
        u32 sC = (u32)__builtin_amdgcn_ds_bpermute(s2x4, (int)pk01);                  \
        u32 sD = (u32)__builtin_amdgcn_ds_bpermute(s2x4, (int)pk23);                  \
        HU bh;                                                                        \
        if (quad < 2) { bh.u[0]=sA; bh.u[1]=sB; bh.u[2]=sC; bh.u[3]=sD; }             \
        else if (wid == 0) { bh.u[0]=0u; bh.u[1]=0u; bh.u[2]=0u; bh.u[3]=0u; }        \
        else if (wid <= 2) { bh = (G) ? x2g1 : pfx; }                                 \
        else { bh.u[0]=(quad==2)?BIAS1:0u; bh.u[1]=0u; bh.u[2]=0u; bh.u[3]=0u; }      \
        _Pragma("unroll")                                                             \
        for (int mt = 0; mt < 4; ++mt)                                                \
            CARR[mt] = __builtin_amdgcn_mfma_f32_16x16x32_f16(WH[mt], bh.h, CARR[mt], 0, 0, 0); \
        float h4[4];                                                                  \
        _Pragma("unroll")                                                             \
        for (int r = 0; r < 4; ++r) {                                                 \
            float gi = fsig(CARR[0][r]);                                              \
            float gf = fsig(CARR[1][r]);                                              \
            float gg = ftanh(CARR[2][r]);                                             \
            float go = fsig(CARR[3][r]);                                              \
            float c  = gf * c_st[r] + gi * gg;                                        \
            c_st[r] = c;                                                              \
            h4[r] = go * ftanh(c);                                                    \
        }                                                                             \
        pk01 = pk2h(h4[0], h4[1]);                                                    \
        pk23 = pk2h(h4[2], h4[3]);                                                    \
        if (wid == 0) {                                                               \
            u32* f1 = (u32*)&poolH[F1o + ((wp * 2 + (G)) * 16 + nl) * 16 + quad * 4]; \
            f1[0] = pk01; f1[1] = pk23;                                               \
        } else if (wid <= 2) {                                                        \
            const int ownX = (wid == 1) ? XAo : XBo;                                  \
            u32* xo = (u32*)&poolH[ownX + ((G) * 16 + nl) * 16 + quad * 4];           \
            xo[0] = pk01; xo[1] = pk23;                                               \
            const int ub = (wid == 1) ? 0 : 16;                                       \
            u32* f2 = (u32*)&poolH[F2o + ((wp * 2 + (G)) * 16 + nl) * 32 + ub + quad * 4]; \
            f2[0] = pk01; f2[1] = pk23;                                               \
            if ((G) == 0) {                                                           \
                const int sibX = (wid == 1) ? XBo : XAo;                              \
                x2g1.h = *(const hv8*)&poolH[sibX + (0 * 16 + nl) * 16 + (quad & 1) * 8]; \
            }                                                                         \
        } else {                                                                      \
            u32* f3 = (u32*)&poolH[F3o + ((G) * 16 + nl) * 16 + quad * 4];            \
            f3[0] = pk01; f3[1] = pk23;                                               \
        }                                                                             \
    }

    const int NI = T_ / 2 + 2;   // 102 barrier intervals, 2 timesteps each
    for (int s = 0; s < NI; ++s) {
        const int pp = (s - 1) & 1, wp = s & 1;
        bool act;
        if (wid == 0)      act = (s < T_ / 2);             // L1: t=2s,2s+1
        else if (wid <= 2) act = (s >= 1 && s <= T_ / 2);  // L2: t=2s-2,2s-1
        else               act = (s >= 2);                 // L3: t=2s-4,2s-3

        if (act) {
            fv4 C0[4] = {Z4, Z4, Z4, Z4};
            fv4 C1[4] = {Z4, Z4, Z4, Z4};
            HU pfx, x2g1;   // w1/w2 other-half h2 (prev-interval slot1 / bounded-skew g0)

            // ---- off-chain: Gx into C0/C1 ----
            if (wid == 0) {
                #pragma unroll
                for (int g = 0; g < 2; ++g) {
                    HU bx0, bx1;
                    bx0.u[0] = pk2h(xc[g][0][0], xc[g][0][1]);
                    bx0.u[1] = pk2h(xc[g][0][2], xc[g][0][3]);
                    bx0.u[2] = pk2h(xc[g][1][0], xc[g][1][1]);
                    bx0.u[3] = pk2h(xc[g][1][2], xc[g][1][3]);
                    if (quad == 0) {
                        bx1.u[0] = pk2h(xc[g][2][0], xc[g][2][1]);
                        bx1.u[1] = pk2h(xc[g][2][2], xc[g][2][3]);
                        bx1.u[2] = BIAS1; bx1.u[3] = 0u;
                    } else { bx1.u[0]=0u; bx1.u[1]=0u; bx1.u[2]=0u; bx1.u[3]=0u; }
                    #pragma unroll
                    for (int mt = 0; mt < 4; ++mt) {
                        fv4* Cg = g ? C1 : C0;   // g is literal post-unroll
                        Cg[mt] = __builtin_amdgcn_mfma_f32_16x16x32_f16(WI0[mt], bx0.h, Cg[mt], 0, 0, 0);
                        Cg[mt] = __builtin_amdgcn_mfma_f32_16x16x32_f16(WI1[mt], bx1.h, Cg[mt], 0, 0, 0);
                    }
                }
                // rotate x pipeline; issue next-next loads (1 interval of vmcnt slack)
                #pragma unroll
                for (int g = 0; g < 2; ++g) { xc[g][0]=xn[g][0]; xc[g][1]=xn[g][1]; xc[g][2]=xn[g][2]; }
                #pragma unroll
                for (int g = 0; g < 2; ++g) {
                    int t = 2 * s + 4 + g;
                    if (t < T_) {
                        xn[g][0] = *(const fv4*)(xb + t * 36 + quad * 8);
                        xn[g][1] = *(const fv4*)(xb + t * 36 + quad * 8 + 4);
                        xn[g][2] = *(const fv4*)(xb + t * 36 + 32);
                    }
                }
            } else if (wid <= 2) {
                HU pf0, pf1;
                pf0.h = *(const hv8*)&poolH[F1o + ((pp * 2 + 0) * 16 + nl) * 16 + (quad & 1) * 8];
                pf1.h = *(const hv8*)&poolH[F1o + ((pp * 2 + 1) * 16 + nl) * 16 + (quad & 1) * 8];
                {
                    const int sibX = (wid == 1) ? XBo : XAo;
                    pfx.h = *(const hv8*)&poolH[sibX + (1 * 16 + nl) * 16 + (quad & 1) * 8];
                }
                HU b0, b1;
                if (quad < 2)      { b0 = pf0; b1 = pf1; }
                else if (quad == 2){ b0.u[0]=BIAS1; b0.u[1]=0u; b0.u[2]=0u; b0.u[3]=0u; b1 = b0; }
                else               { b0.u[0]=0u; b0.u[1]=0u; b0.u[2]=0u; b0.u[3]=0u; b1 = b0; }
                #pragma unroll
                for (int mt = 0; mt < 4; ++mt) {
                    C0[mt] = __builtin_amdgcn_mfma_f32_16x16x32_f16(WI0[mt], b0.h, C0[mt], 0, 0, 0);
                    C1[mt] = __builtin_amdgcn_mfma_f32_16x16x32_f16(WI0[mt], b1.h, C1[mt], 0, 0, 0);
                }
            } else {
                HU b0, b1;
                b0.h = *(const hv8*)&poolH[F2o + ((pp * 2 + 0) * 16 + nl) * 32 + quad * 8];
                b1.h = *(const hv8*)&poolH[F2o + ((pp * 2 + 1) * 16 + nl) * 32 + quad * 8];
                #pragma unroll
                for (int mt = 0; mt < 4; ++mt) {
                    C0[mt] = __builtin_amdgcn_mfma_f32_16x16x32_f16(WI0[mt], b0.h, C0[mt], 0, 0, 0);
                    C1[mt] = __builtin_amdgcn_mfma_f32_16x16x32_f16(WI0[mt], b1.h, C1[mt], 0, 0, 0);
                }
            }

            // ---- serial chain: two timesteps ----
            DO_STEP(C0, 0)
            DO_STEP(C1, 1)
        }
        // LDS-visibility barrier only (no vmcnt drain; x prefetch has 1-interval slack)
        asm volatile("s_waitcnt lgkmcnt(0)\n\ts_barrier" ::: "memory");
    }

    // ---- epilogue: out[b][j] = h3(T-1) . M[:,j] + v[j]   (t=199 -> F3 slot 1) ----
    if (tid < ROWS * 6) {
        int row = tid / 6, j = tid - (tid / 6) * 6;
        float acc = vsh[j];
        const int hb = F3o + 16 * 16 + row * 16;
        #pragma unroll
        for (int u = 0; u < 16; ++u)
            acc += (float)poolH[hb + u] * Msh[u * 6 + j];
        outp[(b0 + row) * 6 + j] = acc;
    }
#undef DO_STEP
}

extern "C" void kernel_launch(void* const* d_in, const int* in_sizes, int n_in,
                              void* d_out, int out_size, void* d_ws, size_t ws_size,
                              hipStream_t stream) {
    const float* x     = (const float*)d_in[0];
    const float* Wih1  = (const float*)d_in[1];
    const float* Whh1  = (const float*)d_in[2];
    const float* bih1  = (const float*)d_in[3];
    const float* bhh1  = (const float*)d_in[4];
    const float* Wih2  = (const float*)d_in[5];
    const float* Whh2  = (const float*)d_in[6];
    const float* bih2  = (const float*)d_in[7];
    const float* bhh2  = (const float*)d_in[8];
    const float* Wih3  = (const float*)d_in[9];
    const float* Whh3  = (const float*)d_in[10];
    const float* bih3  = (const float*)d_in[11];
    const float* bhh3  = (const float*)d_in[12];
    const float* W_fc1 = (const float*)d_in[13];
    const float* b_fc1 = (const float*)d_in[14];
    const float* W_fc2 = (const float*)d_in[15];
    const float* b_fc2 = (const float*)d_in[16];
    const float* W_cls = (const float*)d_in[17];
    const float* b_cls = (const float*)d_in[18];

    lstm_fused<<<512, 256, 0, stream>>>(x,
        Wih1, Whh1, bih1, bhh1,
        Wih2, Whh2, bih2, bhh2,
        Wih3, Whh3, bih3, bhh3,
        W_fc1, b_fc1, W_fc2, b_fc2, W_cls, b_cls,
        (float*)d_out);
}